// Round 3
// baseline (505.475 us; speedup 1.0000x reference)
//
#include <hip/hip_runtime.h>
#include <math.h>

#define NN 50000
#define NE 800000
#define DF 128
#define GEMM_BLK_ROWS 64            // rows per block (8 waves: 4 row-groups x 2 col-halves)
#define SCAN_BLKS 98                // ceil(NN / 512) blocks per graph for the scan
#define EDGE_BLKS 800               // blocks per graph for deg/scatter (800*256*4 >= NE)

__device__ __forceinline__ unsigned short f2bf(float f) {  // round-to-nearest-even
    unsigned u = __float_as_uint(f);
    return (unsigned short)((u + 0x7FFF + ((u >> 16) & 1)) >> 16);
}
#define BF2F(u) __uint_as_float(((unsigned)(u)) << 16)

typedef __attribute__((ext_vector_type(8))) short bf16x8;
typedef __attribute__((ext_vector_type(4))) float f32x4;

// ---------------- phase 1: degree histogram via scattered atomics (deg arrays L2-resident) ----------------
__global__ __launch_bounds__(256) void deg_kernel(const int* __restrict__ dst1, const int* __restrict__ dst2,
                                                  int* __restrict__ deg1, int* __restrict__ deg2) {
    const int g = blockIdx.x & 1;
    const int bid = blockIdx.x >> 1;
    const int4* __restrict__ d4 = (const int4*)(g ? dst2 : dst1);
    int* __restrict__ deg = g ? deg2 : deg1;
    for (int i = bid * 256 + threadIdx.x; i < NE / 4; i += EDGE_BLKS * 256) {
        int4 d = d4[i];
        atomicAdd(&deg[d.x], 1);
        atomicAdd(&deg[d.y], 1);
        atomicAdd(&deg[d.z], 1);
        atomicAdd(&deg[d.w], 1);
    }
}

// ---------------- phase 2a: per-512-block local exclusive scan + dinv ----------------
__global__ __launch_bounds__(256) void scanA_kernel(const int* __restrict__ deg1, const int* __restrict__ deg2,
                                                    float* __restrict__ dinv1, float* __restrict__ dinv2,
                                                    int* __restrict__ rp1, int* __restrict__ rp2,
                                                    int* __restrict__ psum) {
    __shared__ int sdata[512];
    const int b = blockIdx.x;                 // 0..2*SCAN_BLKS-1
    const int g = (b >= SCAN_BLKS) ? 1 : 0;
    const int lb = b - g * SCAN_BLKS;
    const int* __restrict__ deg = g ? deg2 : deg1;
    float* __restrict__ dinv = g ? dinv2 : dinv1;
    int* __restrict__ rp = g ? rp2 : rp1;
    const int t = threadIdx.x;
    const int i0 = lb * 512 + t, i1 = i0 + 256;
    int v0 = (i0 < NN) ? deg[i0] : 0;
    int v1 = (i1 < NN) ? deg[i1] : 0;
    if (i0 < NN) dinv[i0] = rsqrtf((float)v0 + 1.0f);
    if (i1 < NN) dinv[i1] = rsqrtf((float)v1 + 1.0f);
    sdata[t] = v0; sdata[t + 256] = v1;
    __syncthreads();
    #pragma unroll
    for (int off = 1; off < 512; off <<= 1) {
        int a0 = (t >= off) ? sdata[t - off] : 0;
        int a1 = (t + 256 >= off) ? sdata[t + 256 - off] : 0;
        __syncthreads();
        sdata[t] += a0; sdata[t + 256] += a1;
        __syncthreads();
    }
    if (i0 < NN) rp[i0] = sdata[t] - v0;          // local exclusive
    if (i1 < NN) rp[i1] = sdata[t + 256] - v1;
    if (t == 0) psum[b] = sdata[511];             // block total
}

// ---------------- phase 2b: scan the 2x98 block totals (segmented, one block) ----------------
__global__ __launch_bounds__(256) void scanB_kernel(int* __restrict__ psum, int* __restrict__ rp1, int* __restrict__ rp2) {
    __shared__ int s[256];
    const int t = threadIdx.x;
    const int tl = t & 127, seg = t >> 7;
    int v = (tl < SCAN_BLKS) ? psum[seg * SCAN_BLKS + tl] : 0;
    s[t] = v;
    __syncthreads();
    #pragma unroll
    for (int off = 1; off < 128; off <<= 1) {
        int a = (tl >= off) ? s[t - off] : 0;
        __syncthreads();
        s[t] += a;
        __syncthreads();
    }
    if (tl < SCAN_BLKS) psum[seg * SCAN_BLKS + tl] = s[t] - v;   // exclusive block offset
    if (t == 0) { rp1[NN] = NE; rp2[NN] = NE; }
}

// ---------------- phase 2c: add block offsets -> final rp; init scatter cursors ----------------
__global__ __launch_bounds__(256) void scanC_kernel(const int* __restrict__ psum,
                                                    int* __restrict__ rp1, int* __restrict__ rp2,
                                                    int* __restrict__ cur1, int* __restrict__ cur2) {
    const int b = blockIdx.x;
    const int g = (b >= SCAN_BLKS) ? 1 : 0;
    const int lb = b - g * SCAN_BLKS;
    int* __restrict__ rp = g ? rp2 : rp1;
    int* __restrict__ cur = g ? cur2 : cur1;
    const int o = psum[b];
    const int i0 = lb * 512 + threadIdx.x, i1 = i0 + 256;
    if (i0 < NN) { int r = rp[i0] + o; rp[i0] = r; cur[i0] = r; }
    if (i1 < NN) { int r = rp[i1] + o; rp[i1] = r; cur[i1] = r; }
}

// ---------------- phase 3: scatter edges into CSR slots via atomic cursors ----------------
__global__ __launch_bounds__(256) void scatter_kernel(const int* __restrict__ src1, const int* __restrict__ dst1,
                                                      const int* __restrict__ src2, const int* __restrict__ dst2,
                                                      const float* __restrict__ dinv1, const float* __restrict__ dinv2,
                                                      int* __restrict__ cur1, int* __restrict__ cur2,
                                                      int2* __restrict__ pk1, int2* __restrict__ pk2) {
    const int g = blockIdx.x & 1;
    const int bid = blockIdx.x >> 1;
    const int4* __restrict__ s4 = (const int4*)(g ? src2 : src1);
    const int4* __restrict__ d4 = (const int4*)(g ? dst2 : dst1);
    const float* __restrict__ dv = g ? dinv2 : dinv1;
    int* __restrict__ cur = g ? cur2 : cur1;
    int2* __restrict__ pk = g ? pk2 : pk1;
    for (int i = bid * 256 + threadIdx.x; i < NE / 4; i += EDGE_BLKS * 256) {
        int4 s = s4[i]; int4 d = d4[i];
        float c0 = dv[s.x], c1 = dv[s.y], c2 = dv[s.z], c3 = dv[s.w];
        int p0 = atomicAdd(&cur[d.x], 1);
        int p1 = atomicAdd(&cur[d.y], 1);
        int p2 = atomicAdd(&cur[d.z], 1);
        int p3 = atomicAdd(&cur[d.w], 1);
        pk[p0] = make_int2(s.x, __float_as_int(c0));
        pk[p1] = make_int2(s.y, __float_as_int(c1));
        pk[p2] = make_int2(s.z, __float_as_int(c2));
        pk[p3] = make_int2(s.w, __float_as_int(c3));
    }
}

// ---------------- W prep: emit W as bf16 hi/lo in EXACT MFMA fragment order ----------------
// Per layer, 32768 shorts = 64 KB laid out [hl(2)][colhalf(2)][grp=nt*4+ks(16)][lane(64)][e(8)].
// Fragment (hl,h,nt,ks,lane=(kg,lm),e) = bf16 of W^T[col=h*64+nt*16+lm][k=ks*32+kg*8+e].
// GEMM stages this linearly into LDS; every ds_read_b128 is lane-linear 1024B (conflict-free).
__global__ __launch_bounds__(256) void wprep_kernel(const float* __restrict__ W1, const float* __restrict__ W2,
                                                    const float* __restrict__ W3, const float* __restrict__ W4,
                                                    unsigned short* __restrict__ Wpk) {
    const int u = blockIdx.x * 256 + threadIdx.x;   // 0..131071
    const int layer = u >> 15;
    const int r = u & 32767;
    const int fidx = r >> 3, e = r & 7;
    const int lane = fidx & 63;
    const int q = fidx >> 6;             // 0..63
    const int grp = q & 15, hh = q >> 4; // hh = hl*2 + h
    const int hl = hh >> 1, h = hh & 1;
    const int nt = grp >> 2, ks = grp & 3;
    const int kg = lane >> 4, lm = lane & 15;
    const int ncol = h * 64 + nt * 16 + lm;
    const int kk = ks * 32 + kg * 8 + e;
    const float* __restrict__ W = layer == 0 ? W1 : layer == 1 ? W2 : layer == 2 ? W3 : W4;
    float v = W[kk * DF + ncol];
    unsigned short hi = f2bf(v);
    Wpk[u] = hl ? f2bf(v - BF2F(hi)) : hi;
}

// ---------------- H = X @ W via bf16x3-split MFMA, W fragments staged in LDS ----------------
// 8 waves: w = rg(4) x h(2). Wave computes rows rb..rb+15 x cols h*64..h*64+63 (4 nt tiles).
// A-frag: m=lm, k=kg*8+e (per 32-k block ks). D-frag: col=lm, row=kg*4+r (verified layout).
// acc = ah*bh; accl = al*bh + ah*bl  (split accumulators for shorter MFMA dep chains).
__global__ __launch_bounds__(512, 4) void gemm_mfma_kernel(const float* __restrict__ X,
                                                           const unsigned short* __restrict__ Wpk,
                                                           unsigned short* __restrict__ Hhi,
                                                           unsigned short* __restrict__ Hlo, int n) {
    __shared__ __align__(16) unsigned short smem[32768];   // 64 KB, mirrors Wpk layer layout
    const int t = threadIdx.x;
    const int lane = t & 63, w = t >> 6;
    const int h = w >> 2, rg = w & 3;
    const int lm = lane & 15, kg = lane >> 4;
    const int rb = blockIdx.x * GEMM_BLK_ROWS + rg * 16;
    const int row = rb + lm;

    // stage permuted W (hi+lo) into LDS: 4096 x 16B linear copy
    {
        const float4* __restrict__ g4 = (const float4*)Wpk;
        float4* s4 = (float4*)smem;
        #pragma unroll
        for (int i = 0; i < 8; i++) s4[t + 512 * i] = g4[t + 512 * i];
    }

    // load + split A fragments (read X once; hi/lo bf16 in registers) while stage lands
    bf16x8 ah[4], al[4];
    #pragma unroll
    for (int ks = 0; ks < 4; ks++) {
        float4 x0 = make_float4(0.f, 0.f, 0.f, 0.f), x1 = x0;
        if (row < n) {
            const float* xp = X + (size_t)row * DF + ks * 32 + kg * 8;
            x0 = *(const float4*)xp;
            x1 = *(const float4*)(xp + 4);
        }
        float xv[8] = {x0.x, x0.y, x0.z, x0.w, x1.x, x1.y, x1.z, x1.w};
        #pragma unroll
        for (int e = 0; e < 8; e++) {
            unsigned short hi = f2bf(xv[e]);
            float rem = xv[e] - BF2F(hi);
            ah[ks][e] = (short)hi;
            al[ks][e] = (short)f2bf(rem);
        }
    }
    __syncthreads();

    f32x4 acc[4], accl[4];
    #pragma unroll
    for (int nt = 0; nt < 4; nt++) { acc[nt] = (f32x4){0.f, 0.f, 0.f, 0.f}; accl[nt] = acc[nt]; }

    const unsigned short* __restrict__ bhb = smem + ((size_t)(h * 16) * 64 + lane) * 8;
    const unsigned short* __restrict__ blb = smem + ((size_t)((2 + h) * 16) * 64 + lane) * 8;
    #pragma unroll
    for (int nt = 0; nt < 4; nt++) {
        #pragma unroll
        for (int ks = 0; ks < 4; ks++) {
            const int grp = nt * 4 + ks;
            bf16x8 bh = *(const bf16x8*)(bhb + (size_t)grp * 512);
            bf16x8 bl = *(const bf16x8*)(blb + (size_t)grp * 512);
            acc[nt]  = __builtin_amdgcn_mfma_f32_16x16x32_bf16(ah[ks], bh, acc[nt], 0, 0, 0);
            accl[nt] = __builtin_amdgcn_mfma_f32_16x16x32_bf16(al[ks], bh, accl[nt], 0, 0, 0);
            accl[nt] = __builtin_amdgcn_mfma_f32_16x16x32_bf16(ah[ks], bl, accl[nt], 0, 0, 0);
        }
    }

    // epilogue: D layout col=lm, row=kg*4+r; write bf16 hi + bf16 lo (no fp32 H)
    const int rwb = rb + kg * 4;
    #pragma unroll
    for (int r = 0; r < 4; r++) {
        const int ro = rwb + r;
        if (ro < n) {
            #pragma unroll
            for (int nt = 0; nt < 4; nt++) {
                const int col = h * 64 + nt * 16 + lm;
                float v = acc[nt][r] + accl[nt][r];
                unsigned short hi = f2bf(v);
                Hhi[(size_t)ro * DF + col] = hi;
                Hlo[(size_t)ro * DF + col] = f2bf(v - BF2F(hi));
            }
        }
    }
}

// ---------------- aggregation: one wave per dst node, bf16 gathers ----------------
// out[i] = act( dinv[i]*sum coef[e]*Hhi[src[e]] + dinv[i]^2*(Hhi[i]+Hlo[i]) + b )
__global__ __launch_bounds__(256) void agg_kernel(const unsigned short* __restrict__ Hhi,
                                                  const unsigned short* __restrict__ Hlo,
                                                  const int* __restrict__ rp, const int2* __restrict__ pk,
                                                  const float* __restrict__ dinv, const float* __restrict__ bias,
                                                  float* __restrict__ out, int n, int act) {
    const int lane = threadIdx.x & 63;
    const int sub = lane & 31;
    const int half = lane >> 5;
    const int i = blockIdx.x * 4 + (threadIdx.x >> 6);
    if (i >= n) return;
    const int start = rp[i];
    const int end = rp[i + 1];
    float ax = 0.f, ay = 0.f, az = 0.f, aw = 0.f;
    const unsigned short* __restrict__ Hbc = Hhi + 4 * sub;
    for (int base = start; base < end; base += 64) {
        int cnt = end - base;
        if (cnt > 64) cnt = 64;
        int msrc = 0;
        float mdv = 0.f;
        if (lane < cnt) {  // coalesced 8B batch load of packed (src, coef)
            int2 pv = pk[base + lane];
            msrc = pv.x;
            mdv = __int_as_float(pv.y);
        }
        for (int j = 0; j < cnt; j += 16) {  // 16 edges per iter; 8 x 8B gathers in flight per half
            int e0 = j + half;               // halves take even/odd edges; pads have mdv==0
            int s[8]; float d[8];
            #pragma unroll
            for (int k = 0; k < 8; k++) {
                s[k] = __shfl(msrc, e0 + 2 * k);
                d[k] = __shfl(mdv, e0 + 2 * k);
            }
            ushort4 hb[8];
            #pragma unroll
            for (int k = 0; k < 8; k++) hb[k] = *(const ushort4*)(Hbc + (size_t)s[k] * DF);
            #pragma unroll
            for (int k = 0; k < 8; k++) {
                ax = fmaf(d[k], BF2F(hb[k].x), ax);
                ay = fmaf(d[k], BF2F(hb[k].y), ay);
                az = fmaf(d[k], BF2F(hb[k].z), az);
                aw = fmaf(d[k], BF2F(hb[k].w), aw);
            }
        }
    }
    // fold halves: lanes 0-31 += lanes 32-63
    ax += __shfl_down(ax, 32); ay += __shfl_down(ay, 32);
    az += __shfl_down(az, 32); aw += __shfl_down(aw, 32);
    if (half == 0) {
        float di = dinv[i];
        float dii = di * di;
        ushort4 hh4 = *(const ushort4*)(Hhi + (size_t)i * DF + 4 * sub);   // self term hi+lo ~ fp32
        ushort4 hl4 = *(const ushort4*)(Hlo + (size_t)i * DF + 4 * sub);
        float4 bv = *(const float4*)(bias + 4 * sub);
        float hx = BF2F(hh4.x) + BF2F(hl4.x);
        float hy = BF2F(hh4.y) + BF2F(hl4.y);
        float hz = BF2F(hh4.z) + BF2F(hl4.z);
        float hw = BF2F(hh4.w) + BF2F(hl4.w);
        float ox = fmaf(di, ax, fmaf(dii, hx, bv.x));
        float oy = fmaf(di, ay, fmaf(dii, hy, bv.y));
        float oz = fmaf(di, az, fmaf(dii, hz, bv.z));
        float ow = fmaf(di, aw, fmaf(dii, hw, bv.w));
        if (act == 0) {  // ELU
            ox = ox > 0.f ? ox : expm1f(ox);
            oy = oy > 0.f ? oy : expm1f(oy);
            oz = oz > 0.f ? oz : expm1f(oz);
            ow = ow > 0.f ? ow : expm1f(ow);
        } else {  // ReLU
            ox = fmaxf(ox, 0.f); oy = fmaxf(oy, 0.f);
            oz = fmaxf(oz, 0.f); ow = fmaxf(ow, 0.f);
        }
        float4 ov; ov.x = ox; ov.y = oy; ov.z = oz; ov.w = ow;
        *(float4*)(out + (size_t)i * DF + 4 * sub) = ov;
    }
}

extern "C" void kernel_launch(void* const* d_in, const int* in_sizes, int n_in,
                              void* d_out, int out_size, void* d_ws, size_t ws_size,
                              hipStream_t stream) {
    const float* x  = (const float*)d_in[0];
    const float* W1 = (const float*)d_in[1];
    const float* b1 = (const float*)d_in[2];
    const float* W2 = (const float*)d_in[3];
    const float* b2 = (const float*)d_in[4];
    const float* W3 = (const float*)d_in[5];
    const float* b3 = (const float*)d_in[6];
    const float* W4 = (const float*)d_in[7];
    const float* b4 = (const float*)d_in[8];
    const int* ei1 = (const int*)d_in[9];
    const int* ei2 = (const int*)d_in[10];
    const int *src1 = ei1, *dst1 = ei1 + NE;
    const int *src2 = ei2, *dst2 = ei2 + NE;

    // ---- workspace carve-out (512B aligned), ~66 MB ----
    char* ws = (char*)d_ws;
    size_t off = 0;
    auto carve = [&](size_t bytes) -> void* {
        void* p = (void*)(ws + off);
        off += (bytes + 511) & ~(size_t)511;
        return p;
    };
    int* deg1 = (int*)carve((size_t)NN * 4);
    int* deg2 = (int*)carve((size_t)NN * 4);
    size_t zero_bytes = off;                         // deg1+deg2 zeroed
    int* psum = (int*)carve((size_t)2 * SCAN_BLKS * 4);
    int* cur1 = (int*)carve((size_t)NN * 4);
    int* cur2 = (int*)carve((size_t)NN * 4);
    float* dinv1 = (float*)carve((size_t)NN * 4);
    float* dinv2 = (float*)carve((size_t)NN * 4);
    int* rp1 = (int*)carve((size_t)(NN + 1) * 4);
    int* rp2 = (int*)carve((size_t)(NN + 1) * 4);
    int2* pk1 = (int2*)carve((size_t)NE * 8);
    int2* pk2 = (int2*)carve((size_t)NE * 8);
    unsigned short* Hhi = (unsigned short*)carve((size_t)NN * DF * 2);   // 12.8 MB
    unsigned short* Hlo = (unsigned short*)carve((size_t)NN * DF * 2);   // 12.8 MB
    float* hbuf = (float*)carve((size_t)NN * DF * 4);                    // 25.6 MB
    unsigned short* Wpk = (unsigned short*)carve((size_t)4 * 32768 * 2); // 256 KB, fragment-ordered

    float* outz  = (float*)d_out;
    float* outxr = (float*)d_out + (size_t)NN * DF;

    const int gGemm = (NN + GEMM_BLK_ROWS - 1) / GEMM_BLK_ROWS;   // 782
    const int gAgg = (NN + 3) / 4;
    const int WL = 32768;                                 // Wpk shorts per layer

    // ---- preprocessing: wprep -> deg -> scan(A/B/C) -> scatter ----
    hipMemsetAsync(deg1, 0, zero_bytes, stream);
    wprep_kernel<<<512, 256, 0, stream>>>(W1, W2, W3, W4, Wpk);
    deg_kernel<<<2 * EDGE_BLKS, 256, 0, stream>>>(dst1, dst2, deg1, deg2);
    scanA_kernel<<<2 * SCAN_BLKS, 256, 0, stream>>>(deg1, deg2, dinv1, dinv2, rp1, rp2, psum);
    scanB_kernel<<<1, 256, 0, stream>>>(psum, rp1, rp2);
    scanC_kernel<<<2 * SCAN_BLKS, 256, 0, stream>>>(psum, rp1, rp2, cur1, cur2);
    scatter_kernel<<<2 * EDGE_BLKS, 256, 0, stream>>>(src1, dst1, src2, dst2, dinv1, dinv2,
                                                      cur1, cur2, pk1, pk2);

    // ---- layer 1: ELU(gcn(x, ei1, W1, b1)) -> hbuf ----
    gemm_mfma_kernel<<<gGemm, 512, 0, stream>>>(x, Wpk, Hhi, Hlo, NN);
    agg_kernel<<<gAgg, 256, 0, stream>>>(Hhi, Hlo, rp1, pk1, dinv1, b1, hbuf, NN, 0);
    // ---- layer 2: z = ELU(gcn(hbuf, ei2, W2, b2)) -> d_out ----
    gemm_mfma_kernel<<<gGemm, 512, 0, stream>>>(hbuf, Wpk + WL, Hhi, Hlo, NN);
    agg_kernel<<<gAgg, 256, 0, stream>>>(Hhi, Hlo, rp2, pk2, dinv2, b2, outz, NN, 0);
    // ---- layer 3: ELU(gcn(z, ei1, W3, b3)) -> hbuf ----
    gemm_mfma_kernel<<<gGemm, 512, 0, stream>>>(outz, Wpk + 2 * WL, Hhi, Hlo, NN);
    agg_kernel<<<gAgg, 256, 0, stream>>>(Hhi, Hlo, rp1, pk1, dinv1, b3, hbuf, NN, 0);
    // ---- layer 4: xr = ReLU(gcn(hbuf, ei2, W4, b4)) -> d_out[N*DF:] ----
    gemm_mfma_kernel<<<gGemm, 512, 0, stream>>>(hbuf, Wpk + 3 * WL, Hhi, Hlo, NN);
    agg_kernel<<<gAgg, 256, 0, stream>>>(Hhi, Hlo, rp2, pk2, dinv2, b4, outxr, NN, 1);
}

// Round 4
// 457.076 us; speedup vs baseline: 1.1059x; 1.1059x over previous
//
#include <hip/hip_runtime.h>
#include <math.h>

#define NN 50000
#define NE 800000
#define DF 128
#define NBKT 128                    // direct 128-way dst binning
#define BKT_W 391                   // 128*391 = 50048 >= NN; same width as old chunks
#define BK_CAP 60                   // LDS bucket capacity (61.4 KB total)
#define BK_TH 36                    // flush threshold; slack 24 >> Poisson(2) tail
#define BSTG_CAP 7680               // staged edges per bucket: mean 6256, +18 sigma (proven cap)
#define BIN_BLOCKS 512              // 256 per graph
#define GEMM_BLK_ROWS 64            // rows per block (8 waves: 4 row-groups x 2 col-halves)

__device__ __forceinline__ unsigned short f2bf(float f) {  // round-to-nearest-even
    unsigned u = __float_as_uint(f);
    return (unsigned short)((u + 0x7FFF + ((u >> 16) & 1)) >> 16);
}
#define BF2F(u) __uint_as_float(((unsigned)(u)) << 16)

typedef __attribute__((ext_vector_type(8))) short bf16x8;
typedef __attribute__((ext_vector_type(4))) float f32x4;

// ---------------- phase 1: single-pass 128-way bin via LDS-atomic rank + batched flush ----------------
// Replaces old bin(8-way ballot) + subbin(16-way ballot): one edge pass instead of two.
__global__ __launch_bounds__(256) void bin_kernel(const int* __restrict__ src1, const int* __restrict__ dst1,
                                                  const int* __restrict__ src2, const int* __restrict__ dst2,
                                                  int2* __restrict__ stg, int* __restrict__ stgcnt) {
    __shared__ int2 buck[NBKT][BK_CAP];   // 61440 B
    __shared__ int bcnt[NBKT];
    __shared__ int gbase[NBKT];
    __shared__ int fcnt[NBKT];
    const int t = threadIdx.x;
    const int g = (blockIdx.x >= BIN_BLOCKS / 2) ? 1 : 0;
    const int bid = blockIdx.x - g * (BIN_BLOCKS / 2);
    const int nb = BIN_BLOCKS / 2;
    const int* __restrict__ srcv = g ? src2 : src1;
    const int* __restrict__ dstv = g ? dst2 : dst1;
    int2* __restrict__ stg_g = stg + (size_t)g * NBKT * BSTG_CAP;
    int* __restrict__ cnt_g = stgcnt + g * NBKT;
    if (t < NBKT) bcnt[t] = 0;
    __syncthreads();
    for (int base = bid * 256; base < NE; base += nb * 256) {
        const int e = base + t;
        if (e < NE) {
            int2 ed; ed.x = srcv[e]; ed.y = dstv[e];
            const int p = ed.y / BKT_W;
            int rank = atomicAdd(&bcnt[p], 1);
            if (rank < BK_CAP) {
                buck[p][rank] = ed;
            } else {                                   // ~never: direct write fallback
                int gb = atomicAdd(&cnt_g[p], 1);
                if (gb < BSTG_CAP) stg_g[(size_t)p * BSTG_CAP + gb] = ed;
            }
        }
        __syncthreads();
        const bool last = (base + nb * 256) >= NE;
        if (t < NBKT) {
            int c = bcnt[t];
            if (c > BK_CAP) c = BK_CAP;
            const bool fl = (c >= BK_TH) || (last && c > 0);
            fcnt[t] = fl ? c : 0;
            gbase[t] = fl ? atomicAdd(&cnt_g[t], c) : -1;
            if (fl) bcnt[t] = 0;
        }
        __syncthreads();
        for (int q = 0; q < NBKT; q++) {              // uniform scalar branch per bucket
            const int gb = gbase[q];
            if (gb < 0) continue;
            const int c = fcnt[q];
            for (int i = t; i < c; i += 256)
                if (gb + i < BSTG_CAP)
                    stg_g[(size_t)q * BSTG_CAP + gb + i] = buck[q][i];
        }
        __syncthreads();
    }
}

// ---------------- phase 2: segmented scan of the 2x128 bucket counts -> bucket edge bases ----------------
// Two independent 128-scans by wave-carry construction (w0->w1 for graph0, w2->w3 for graph1).
__global__ __launch_bounds__(256) void chunkscan_kernel(const int* __restrict__ bktcnt, int* __restrict__ cbase,
                                                        int* __restrict__ rp1, int* __restrict__ rp2) {
    __shared__ int wtot[4];
    const int t = threadIdx.x, lane = t & 63, w = t >> 6;
    int v = bktcnt[t];
    int x = v;
    #pragma unroll
    for (int off = 1; off < 64; off <<= 1) { int y = __shfl_up(x, off); if (lane >= off) x += y; }
    if (lane == 63) wtot[w] = x;
    __syncthreads();
    int add = (w == 1) ? wtot[0] : ((w == 3) ? wtot[2] : 0);
    cbase[t] = x - v + add;
    if (t == 0) { rp1[NN] = NE; rp2[NN] = NE; }
}

// ---------------- phase 3: per-bucket degree hist + LDS scan -> rp + dinv ----------------
__global__ __launch_bounds__(256) void histrp_kernel(const int2* __restrict__ stg, const int* __restrict__ bktcnt,
                                                     const int* __restrict__ cbase,
                                                     int* __restrict__ rp1, float* __restrict__ dinv1,
                                                     int* __restrict__ rp2, float* __restrict__ dinv2) {
    __shared__ int deg[512];
    const int t = threadIdx.x;
    const int b = blockIdx.x & (NBKT - 1), g = blockIdx.x >> 7;
    const int segi = g * NBKT + b;
    int m = bktcnt[segi];
    if (m > BSTG_CAP) m = BSTG_CAP;
    const int2* __restrict__ seg = stg + (size_t)segi * BSTG_CAP;
    int* __restrict__ rp = g ? rp2 : rp1;
    float* __restrict__ dinv = g ? dinv2 : dinv1;
    const int lo = b * BKT_W;
    int hi = lo + BKT_W;
    if (hi > NN) hi = NN;
    const int nw = hi - lo;
    deg[t] = 0; deg[t + 256] = 0;
    __syncthreads();
    for (int i = t; i < m; i += 256) atomicAdd(&deg[seg[i].y - lo], 1);
    __syncthreads();
    if (t < nw) dinv[lo + t] = rsqrtf((float)deg[t] + 1.0f);
    if (t + 256 < nw) dinv[lo + t + 256] = rsqrtf((float)deg[t + 256] + 1.0f);
    #pragma unroll
    for (int off = 1; off < 512; off <<= 1) {
        int v0 = (t >= off) ? deg[t - off] : 0;
        int v1 = (t + 256 >= off) ? deg[t + 256 - off] : 0;
        __syncthreads();
        deg[t] += v0; deg[t + 256] += v1;
        __syncthreads();
    }
    const int base = cbase[segi];
    if (t < nw) rp[lo + t] = base + (t ? deg[t - 1] : 0);
    if (t + 256 < nw) rp[lo + t + 256] = base + deg[t + 256 - 1];
}

// ---------------- phase 4: LDS-sorted placement from OWN bucket segment ----------------
__global__ __launch_bounds__(256) void place_kernel(const int2* __restrict__ stg, const int* __restrict__ bktcnt,
                                                    const int* __restrict__ rp1, const int* __restrict__ rp2,
                                                    const float* __restrict__ dinv1, const float* __restrict__ dinv2,
                                                    int2* __restrict__ pk1, int2* __restrict__ pk2) {
    __shared__ int2 sorted[BSTG_CAP];    // 60 KB
    __shared__ int fill[BKT_W];
    __shared__ int rps[BKT_W + 1];
    const int t = threadIdx.x;
    const int b = blockIdx.x & (NBKT - 1), g = blockIdx.x >> 7;
    const int segi = g * NBKT + b;
    int m = bktcnt[segi];
    if (m > BSTG_CAP) m = BSTG_CAP;
    const int2* __restrict__ seg = stg + (size_t)segi * BSTG_CAP;
    const int* __restrict__ rp = g ? rp2 : rp1;
    const float* __restrict__ dinv = g ? dinv2 : dinv1;
    int2* __restrict__ pk = g ? pk2 : pk1;
    const int lo = b * BKT_W;
    int hi = lo + BKT_W;
    if (hi > NN) hi = NN;
    const int nw = hi - lo;
    for (int i = t; i < nw; i += 256) { fill[i] = 0; rps[i] = rp[lo + i]; }
    if (t == 0) rps[nw] = rp[hi];
    __syncthreads();
    const int segbase = rps[0];
    const int total = rps[nw] - segbase;
    for (int i = t; i < m; i += 256) {
        int2 e = seg[i];
        int dl = e.y - lo;
        int lp = rps[dl] - segbase + atomicAdd(&fill[dl], 1);
        if (lp < BSTG_CAP)
            sorted[lp] = make_int2(e.x, __float_as_int(dinv[e.x]));
    }
    __syncthreads();
    for (int i = t; i < total; i += 256)
        pk[segbase + i] = sorted[i];
}

// ---------------- W prep: emit W as bf16 hi/lo in EXACT MFMA fragment order ----------------
// Per layer, 32768 shorts = 64 KB laid out [hl(2)][colhalf(2)][grp=nt*4+ks(16)][lane(64)][e(8)].
// Fragment (hl,h,nt,ks,lane=(kg,lm),e) = bf16 of W^T[col=h*64+nt*16+lm][k=ks*32+kg*8+e].
// GEMM stages this linearly into LDS; every ds_read_b128 is lane-linear 1024B (conflict-free).
__global__ __launch_bounds__(256) void wprep_kernel(const float* __restrict__ W1, const float* __restrict__ W2,
                                                    const float* __restrict__ W3, const float* __restrict__ W4,
                                                    unsigned short* __restrict__ Wpk) {
    const int u = blockIdx.x * 256 + threadIdx.x;   // 0..131071
    const int layer = u >> 15;
    const int r = u & 32767;
    const int fidx = r >> 3, e = r & 7;
    const int lane = fidx & 63;
    const int q = fidx >> 6;             // 0..63
    const int grp = q & 15, hh = q >> 4; // hh = hl*2 + h
    const int hl = hh >> 1, h = hh & 1;
    const int nt = grp >> 2, ks = grp & 3;
    const int kg = lane >> 4, lm = lane & 15;
    const int ncol = h * 64 + nt * 16 + lm;
    const int kk = ks * 32 + kg * 8 + e;
    const float* __restrict__ W = layer == 0 ? W1 : layer == 1 ? W2 : layer == 2 ? W3 : W4;
    float v = W[kk * DF + ncol];
    unsigned short hi = f2bf(v);
    Wpk[u] = hl ? f2bf(v - BF2F(hi)) : hi;
}

// ---------------- H = X @ W via bf16x3-split MFMA, W fragments staged in LDS ----------------
// 8 waves: w = rg(4) x h(2). Wave computes rows rb..rb+15 x cols h*64..h*64+63 (4 nt tiles).
// A-frag: m=lm, k=kg*8+e (per 32-k block ks). D-frag: col=lm, row=kg*4+r (verified layout).
// acc = ah*bh; accl = al*bh + ah*bl  (split accumulators for shorter MFMA dep chains).
__global__ __launch_bounds__(512, 4) void gemm_mfma_kernel(const float* __restrict__ X,
                                                           const unsigned short* __restrict__ Wpk,
                                                           unsigned short* __restrict__ Hhi,
                                                           unsigned short* __restrict__ Hlo, int n) {
    __shared__ __align__(16) unsigned short smem[32768];   // 64 KB, mirrors Wpk layer layout
    const int t = threadIdx.x;
    const int lane = t & 63, w = t >> 6;
    const int h = w >> 2, rg = w & 3;
    const int lm = lane & 15, kg = lane >> 4;
    const int rb = blockIdx.x * GEMM_BLK_ROWS + rg * 16;
    const int row = rb + lm;

    // stage permuted W (hi+lo) into LDS: 4096 x 16B linear copy
    {
        const float4* __restrict__ g4 = (const float4*)Wpk;
        float4* s4 = (float4*)smem;
        #pragma unroll
        for (int i = 0; i < 8; i++) s4[t + 512 * i] = g4[t + 512 * i];
    }

    // load + split A fragments (read X once; hi/lo bf16 in registers) while stage lands
    bf16x8 ah[4], al[4];
    #pragma unroll
    for (int ks = 0; ks < 4; ks++) {
        float4 x0 = make_float4(0.f, 0.f, 0.f, 0.f), x1 = x0;
        if (row < n) {
            const float* xp = X + (size_t)row * DF + ks * 32 + kg * 8;
            x0 = *(const float4*)xp;
            x1 = *(const float4*)(xp + 4);
        }
        float xv[8] = {x0.x, x0.y, x0.z, x0.w, x1.x, x1.y, x1.z, x1.w};
        #pragma unroll
        for (int e = 0; e < 8; e++) {
            unsigned short hi = f2bf(xv[e]);
            float rem = xv[e] - BF2F(hi);
            ah[ks][e] = (short)hi;
            al[ks][e] = (short)f2bf(rem);
        }
    }
    __syncthreads();

    f32x4 acc[4], accl[4];
    #pragma unroll
    for (int nt = 0; nt < 4; nt++) { acc[nt] = (f32x4){0.f, 0.f, 0.f, 0.f}; accl[nt] = acc[nt]; }

    const unsigned short* __restrict__ bhb = smem + ((size_t)(h * 16) * 64 + lane) * 8;
    const unsigned short* __restrict__ blb = smem + ((size_t)((2 + h) * 16) * 64 + lane) * 8;
    #pragma unroll
    for (int nt = 0; nt < 4; nt++) {
        #pragma unroll
        for (int ks = 0; ks < 4; ks++) {
            const int grp = nt * 4 + ks;
            bf16x8 bh = *(const bf16x8*)(bhb + (size_t)grp * 512);
            bf16x8 bl = *(const bf16x8*)(blb + (size_t)grp * 512);
            acc[nt]  = __builtin_amdgcn_mfma_f32_16x16x32_bf16(ah[ks], bh, acc[nt], 0, 0, 0);
            accl[nt] = __builtin_amdgcn_mfma_f32_16x16x32_bf16(al[ks], bh, accl[nt], 0, 0, 0);
            accl[nt] = __builtin_amdgcn_mfma_f32_16x16x32_bf16(ah[ks], bl, accl[nt], 0, 0, 0);
        }
    }

    // epilogue: D layout col=lm, row=kg*4+r; write bf16 hi + bf16 lo (no fp32 H)
    const int rwb = rb + kg * 4;
    #pragma unroll
    for (int r = 0; r < 4; r++) {
        const int ro = rwb + r;
        if (ro < n) {
            #pragma unroll
            for (int nt = 0; nt < 4; nt++) {
                const int col = h * 64 + nt * 16 + lm;
                float v = acc[nt][r] + accl[nt][r];
                unsigned short hi = f2bf(v);
                Hhi[(size_t)ro * DF + col] = hi;
                Hlo[(size_t)ro * DF + col] = f2bf(v - BF2F(hi));
            }
        }
    }
}

// ---------------- aggregation: one wave per dst node, bf16 gathers ----------------
// out[i] = act( dinv[i]*sum coef[e]*Hhi[src[e]] + dinv[i]^2*(Hhi[i]+Hlo[i]) + b )
__global__ __launch_bounds__(256) void agg_kernel(const unsigned short* __restrict__ Hhi,
                                                  const unsigned short* __restrict__ Hlo,
                                                  const int* __restrict__ rp, const int2* __restrict__ pk,
                                                  const float* __restrict__ dinv, const float* __restrict__ bias,
                                                  float* __restrict__ out, int n, int act) {
    const int lane = threadIdx.x & 63;
    const int sub = lane & 31;
    const int half = lane >> 5;
    const int i = blockIdx.x * 4 + (threadIdx.x >> 6);
    if (i >= n) return;
    const int start = rp[i];
    const int end = rp[i + 1];
    float ax = 0.f, ay = 0.f, az = 0.f, aw = 0.f;
    const unsigned short* __restrict__ Hbc = Hhi + 4 * sub;
    for (int base = start; base < end; base += 64) {
        int cnt = end - base;
        if (cnt > 64) cnt = 64;
        int msrc = 0;
        float mdv = 0.f;
        if (lane < cnt) {  // coalesced 8B batch load of packed (src, coef)
            int2 pv = pk[base + lane];
            msrc = pv.x;
            mdv = __int_as_float(pv.y);
        }
        for (int j = 0; j < cnt; j += 16) {  // 16 edges per iter; 8 x 8B gathers in flight per half
            int e0 = j + half;               // halves take even/odd edges; pads have mdv==0
            int s[8]; float d[8];
            #pragma unroll
            for (int k = 0; k < 8; k++) {
                s[k] = __shfl(msrc, e0 + 2 * k);
                d[k] = __shfl(mdv, e0 + 2 * k);
            }
            ushort4 hb[8];
            #pragma unroll
            for (int k = 0; k < 8; k++) hb[k] = *(const ushort4*)(Hbc + (size_t)s[k] * DF);
            #pragma unroll
            for (int k = 0; k < 8; k++) {
                ax = fmaf(d[k], BF2F(hb[k].x), ax);
                ay = fmaf(d[k], BF2F(hb[k].y), ay);
                az = fmaf(d[k], BF2F(hb[k].z), az);
                aw = fmaf(d[k], BF2F(hb[k].w), aw);
            }
        }
    }
    // fold halves: lanes 0-31 += lanes 32-63
    ax += __shfl_down(ax, 32); ay += __shfl_down(ay, 32);
    az += __shfl_down(az, 32); aw += __shfl_down(aw, 32);
    if (half == 0) {
        float di = dinv[i];
        float dii = di * di;
        ushort4 hh4 = *(const ushort4*)(Hhi + (size_t)i * DF + 4 * sub);   // self term hi+lo ~ fp32
        ushort4 hl4 = *(const ushort4*)(Hlo + (size_t)i * DF + 4 * sub);
        float4 bv = *(const float4*)(bias + 4 * sub);
        float hx = BF2F(hh4.x) + BF2F(hl4.x);
        float hy = BF2F(hh4.y) + BF2F(hl4.y);
        float hz = BF2F(hh4.z) + BF2F(hl4.z);
        float hw = BF2F(hh4.w) + BF2F(hl4.w);
        float ox = fmaf(di, ax, fmaf(dii, hx, bv.x));
        float oy = fmaf(di, ay, fmaf(dii, hy, bv.y));
        float oz = fmaf(di, az, fmaf(dii, hz, bv.z));
        float ow = fmaf(di, aw, fmaf(dii, hw, bv.w));
        if (act == 0) {  // ELU
            ox = ox > 0.f ? ox : expm1f(ox);
            oy = oy > 0.f ? oy : expm1f(oy);
            oz = oz > 0.f ? oz : expm1f(oz);
            ow = ow > 0.f ? ow : expm1f(ow);
        } else {  // ReLU
            ox = fmaxf(ox, 0.f); oy = fmaxf(oy, 0.f);
            oz = fmaxf(oz, 0.f); ow = fmaxf(ow, 0.f);
        }
        float4 ov; ov.x = ox; ov.y = oy; ov.z = oz; ov.w = ow;
        *(float4*)(out + (size_t)i * DF + 4 * sub) = ov;
    }
}

extern "C" void kernel_launch(void* const* d_in, const int* in_sizes, int n_in,
                              void* d_out, int out_size, void* d_ws, size_t ws_size,
                              hipStream_t stream) {
    const float* x  = (const float*)d_in[0];
    const float* W1 = (const float*)d_in[1];
    const float* b1 = (const float*)d_in[2];
    const float* W2 = (const float*)d_in[3];
    const float* b2 = (const float*)d_in[4];
    const float* W3 = (const float*)d_in[5];
    const float* b3 = (const float*)d_in[6];
    const float* W4 = (const float*)d_in[7];
    const float* b4 = (const float*)d_in[8];
    const int* ei1 = (const int*)d_in[9];
    const int* ei2 = (const int*)d_in[10];
    const int *src1 = ei1, *dst1 = ei1 + NE;
    const int *src2 = ei2, *dst2 = ei2 + NE;

    // ---- workspace carve-out (512B aligned), ~83 MB ----
    char* ws = (char*)d_ws;
    size_t off = 0;
    auto carve = [&](size_t bytes) -> void* {
        void* p = (void*)(ws + off);
        off += (bytes + 511) & ~(size_t)511;
        return p;
    };
    int* stgcnt = (int*)carve((size_t)2 * NBKT * 4);
    size_t zero_bytes = off;                         // stgcnt zeroed
    int* cbase = (int*)carve((size_t)2 * NBKT * 4);
    float* dinv1 = (float*)carve((size_t)NN * 4);
    float* dinv2 = (float*)carve((size_t)NN * 4);
    int* rp1 = (int*)carve((size_t)(NN + 1) * 4);
    int* rp2 = (int*)carve((size_t)(NN + 1) * 4);
    int2* pk1 = (int2*)carve((size_t)NE * 8);
    int2* pk2 = (int2*)carve((size_t)NE * 8);
    int2* stg = (int2*)carve((size_t)2 * NBKT * BSTG_CAP * 8);           // 15.7 MB
    unsigned short* Hhi = (unsigned short*)carve((size_t)NN * DF * 2);   // 12.8 MB
    unsigned short* Hlo = (unsigned short*)carve((size_t)NN * DF * 2);   // 12.8 MB
    float* hbuf = (float*)carve((size_t)NN * DF * 4);                    // 25.6 MB
    unsigned short* Wpk = (unsigned short*)carve((size_t)4 * 32768 * 2); // 256 KB, fragment-ordered

    float* outz  = (float*)d_out;
    float* outxr = (float*)d_out + (size_t)NN * DF;

    const int gGemm = (NN + GEMM_BLK_ROWS - 1) / GEMM_BLK_ROWS;   // 782
    const int gAgg = (NN + 3) / 4;
    const int gBkt = 2 * NBKT;                            // 256 blocks
    const int WL = 32768;                                 // Wpk shorts per layer

    // ---- preprocessing: wprep -> bin128 -> bucketscan -> histrp -> place ----
    hipMemsetAsync(stgcnt, 0, zero_bytes, stream);
    wprep_kernel<<<512, 256, 0, stream>>>(W1, W2, W3, W4, Wpk);
    bin_kernel<<<BIN_BLOCKS, 256, 0, stream>>>(src1, dst1, src2, dst2, stg, stgcnt);
    chunkscan_kernel<<<1, 256, 0, stream>>>(stgcnt, cbase, rp1, rp2);
    histrp_kernel<<<gBkt, 256, 0, stream>>>(stg, stgcnt, cbase, rp1, dinv1, rp2, dinv2);
    place_kernel<<<gBkt, 256, 0, stream>>>(stg, stgcnt, rp1, rp2, dinv1, dinv2, pk1, pk2);

    // ---- layer 1: ELU(gcn(x, ei1, W1, b1)) -> hbuf ----
    gemm_mfma_kernel<<<gGemm, 512, 0, stream>>>(x, Wpk, Hhi, Hlo, NN);
    agg_kernel<<<gAgg, 256, 0, stream>>>(Hhi, Hlo, rp1, pk1, dinv1, b1, hbuf, NN, 0);
    // ---- layer 2: z = ELU(gcn(hbuf, ei2, W2, b2)) -> d_out ----
    gemm_mfma_kernel<<<gGemm, 512, 0, stream>>>(hbuf, Wpk + WL, Hhi, Hlo, NN);
    agg_kernel<<<gAgg, 256, 0, stream>>>(Hhi, Hlo, rp2, pk2, dinv2, b2, outz, NN, 0);
    // ---- layer 3: ELU(gcn(z, ei1, W3, b3)) -> hbuf ----
    gemm_mfma_kernel<<<gGemm, 512, 0, stream>>>(outz, Wpk + 2 * WL, Hhi, Hlo, NN);
    agg_kernel<<<gAgg, 256, 0, stream>>>(Hhi, Hlo, rp1, pk1, dinv1, b3, hbuf, NN, 0);
    // ---- layer 4: xr = ReLU(gcn(hbuf, ei2, W4, b4)) -> d_out[N*DF:] ----
    gemm_mfma_kernel<<<gGemm, 512, 0, stream>>>(hbuf, Wpk + 3 * WL, Hhi, Hlo, NN);
    agg_kernel<<<gAgg, 256, 0, stream>>>(Hhi, Hlo, rp2, pk2, dinv2, b4, outxr, NN, 1);
}

// Round 5
// 354.285 us; speedup vs baseline: 1.4267x; 1.2901x over previous
//
#include <hip/hip_runtime.h>
#include <math.h>

#define NN 50000
#define NE 800000
#define DF 128
#define NBKT 128                    // direct 128-way dst binning
#define BKT_W 391                   // 128*391 = 50048 >= NN; same width as old chunks
#define BK_CAP 56                   // LDS bucket capacity (57.3 KB total)
#define BK_TH 24                    // flush threshold: arrivals/round ~Poisson(8), flush ~every round
#define EDG_PER_IT 1024             // 4 edges per thread per round
#define BSTG_CAP 7680               // staged edges per bucket: mean 6256, +18 sigma (proven cap)
#define BIN_BLOCKS 512              // 256 per graph
#define GEMM_BLK_ROWS 64            // rows per block (8 waves: 4 row-groups x 2 col-halves)

__device__ __forceinline__ unsigned short f2bf(float f) {  // round-to-nearest-even
    unsigned u = __float_as_uint(f);
    return (unsigned short)((u + 0x7FFF + ((u >> 16) & 1)) >> 16);
}
#define BF2F(u) __uint_as_float(((unsigned)(u)) << 16)

typedef __attribute__((ext_vector_type(8))) short bf16x8;
typedef __attribute__((ext_vector_type(4))) float f32x4;

// ---------------- phase 1: single-pass 128-way bin; LDS-atomic rank, compacted wave-parallel flush ----------------
__global__ __launch_bounds__(256) void bin_kernel(const int* __restrict__ src1, const int* __restrict__ dst1,
                                                  const int* __restrict__ src2, const int* __restrict__ dst2,
                                                  int2* __restrict__ stg, int* __restrict__ stgcnt) {
    __shared__ int2 buck[NBKT][BK_CAP];   // 57344 B
    __shared__ int bcnt[NBKT];
    __shared__ int flq[NBKT], flc[NBKT], flb[NBKT];   // compacted flush list
    __shared__ int fnum[2];                            // parity-indexed slot counter
    const int t = threadIdx.x, lane = t & 63, w = t >> 6;
    const int g = (blockIdx.x >= BIN_BLOCKS / 2) ? 1 : 0;
    const int bid = blockIdx.x - g * (BIN_BLOCKS / 2);
    const int nb = BIN_BLOCKS / 2;
    const int4* __restrict__ s4 = (const int4*)(g ? src2 : src1);
    const int4* __restrict__ d4 = (const int4*)(g ? dst2 : dst1);
    int2* __restrict__ stg_g = stg + (size_t)g * NBKT * BSTG_CAP;
    int* __restrict__ cnt_g = stgcnt + g * NBKT;
    if (t < NBKT) bcnt[t] = 0;
    if (t < 2) fnum[t] = 0;
    __syncthreads();
    int it = 0;
    for (int base = bid * EDG_PER_IT; base < NE; base += nb * EDG_PER_IT, ++it) {
        const int i4 = (base >> 2) + t;
        if (i4 < NE / 4) {
            int4 sv = s4[i4];
            int4 dv = d4[i4];
            #pragma unroll
            for (int k = 0; k < 4; k++) {
                const int ss = k == 0 ? sv.x : k == 1 ? sv.y : k == 2 ? sv.z : sv.w;
                const int dd = k == 0 ? dv.x : k == 1 ? dv.y : k == 2 ? dv.z : dv.w;
                const int p = dd / BKT_W;
                const int rank = atomicAdd(&bcnt[p], 1);
                if (rank < BK_CAP) {
                    buck[p][rank] = make_int2(ss, dd);
                } else {                                   // ~never: direct write fallback
                    int gb = atomicAdd(&cnt_g[p], 1);
                    if (gb < BSTG_CAP) stg_g[(size_t)p * BSTG_CAP + gb] = make_int2(ss, dd);
                }
            }
        }
        __syncthreads();
        const bool last = (base + nb * EDG_PER_IT) >= NE;
        const int par = it & 1;
        if (t < NBKT) {                                   // parallel claim: thread t owns bucket t
            int c = bcnt[t];
            if (c > BK_CAP) c = BK_CAP;
            if ((c >= BK_TH) || (last && c > 0)) {
                const int slot = atomicAdd(&fnum[par], 1);
                flq[slot] = t;
                flc[slot] = c;
                flb[slot] = atomicAdd(&cnt_g[t], c);
                bcnt[t] = 0;
            }
        }
        if (t == 0) fnum[par ^ 1] = 0;                    // reset other parity for next round
        __syncthreads();
        const int nf = fnum[par];
        for (int s = w; s < nf; s += 4) {                 // wave-parallel over flush slots
            const int q = flq[s], c = flc[s], gb = flb[s];
            for (int i = lane; i < c; i += 64)
                if (gb + i < BSTG_CAP)
                    stg_g[(size_t)q * BSTG_CAP + gb + i] = buck[q][i];
        }
        __syncthreads();
    }
}

// ---------------- phase 2: segmented scan of the 2x128 bucket counts -> bucket edge bases ----------------
__global__ __launch_bounds__(256) void chunkscan_kernel(const int* __restrict__ bktcnt, int* __restrict__ cbase,
                                                        int* __restrict__ rp1, int* __restrict__ rp2) {
    __shared__ int wtot[4];
    const int t = threadIdx.x, lane = t & 63, w = t >> 6;
    int v = bktcnt[t];
    int x = v;
    #pragma unroll
    for (int off = 1; off < 64; off <<= 1) { int y = __shfl_up(x, off); if (lane >= off) x += y; }
    if (lane == 63) wtot[w] = x;
    __syncthreads();
    int add = (w == 1) ? wtot[0] : ((w == 3) ? wtot[2] : 0);
    cbase[t] = x - v + add;
    if (t == 0) { rp1[NN] = NE; rp2[NN] = NE; }
}

// ---------------- phase 3: per-bucket degree hist + LDS scan -> rp + dinv ----------------
__global__ __launch_bounds__(256) void histrp_kernel(const int2* __restrict__ stg, const int* __restrict__ bktcnt,
                                                     const int* __restrict__ cbase,
                                                     int* __restrict__ rp1, float* __restrict__ dinv1,
                                                     int* __restrict__ rp2, float* __restrict__ dinv2) {
    __shared__ int deg[512];
    const int t = threadIdx.x;
    const int b = blockIdx.x & (NBKT - 1), g = blockIdx.x >> 7;
    const int segi = g * NBKT + b;
    int m = bktcnt[segi];
    if (m > BSTG_CAP) m = BSTG_CAP;
    const int2* __restrict__ seg = stg + (size_t)segi * BSTG_CAP;
    int* __restrict__ rp = g ? rp2 : rp1;
    float* __restrict__ dinv = g ? dinv2 : dinv1;
    const int lo = b * BKT_W;
    int hi = lo + BKT_W;
    if (hi > NN) hi = NN;
    const int nw = hi - lo;
    deg[t] = 0; deg[t + 256] = 0;
    __syncthreads();
    for (int i = t; i < m; i += 256) atomicAdd(&deg[seg[i].y - lo], 1);
    __syncthreads();
    if (t < nw) dinv[lo + t] = rsqrtf((float)deg[t] + 1.0f);
    if (t + 256 < nw) dinv[lo + t + 256] = rsqrtf((float)deg[t + 256] + 1.0f);
    #pragma unroll
    for (int off = 1; off < 512; off <<= 1) {
        int v0 = (t >= off) ? deg[t - off] : 0;
        int v1 = (t + 256 >= off) ? deg[t + 256 - off] : 0;
        __syncthreads();
        deg[t] += v0; deg[t + 256] += v1;
        __syncthreads();
    }
    const int base = cbase[segi];
    if (t < nw) rp[lo + t] = base + (t ? deg[t - 1] : 0);
    if (t + 256 < nw) rp[lo + t + 256] = base + deg[t + 256 - 1];
}

// ---------------- phase 4: LDS-sorted placement from OWN bucket segment ----------------
__global__ __launch_bounds__(256) void place_kernel(const int2* __restrict__ stg, const int* __restrict__ bktcnt,
                                                    const int* __restrict__ rp1, const int* __restrict__ rp2,
                                                    const float* __restrict__ dinv1, const float* __restrict__ dinv2,
                                                    int2* __restrict__ pk1, int2* __restrict__ pk2) {
    __shared__ int2 sorted[BSTG_CAP];    // 60 KB
    __shared__ int fill[BKT_W];
    __shared__ int rps[BKT_W + 1];
    const int t = threadIdx.x;
    const int b = blockIdx.x & (NBKT - 1), g = blockIdx.x >> 7;
    const int segi = g * NBKT + b;
    int m = bktcnt[segi];
    if (m > BSTG_CAP) m = BSTG_CAP;
    const int2* __restrict__ seg = stg + (size_t)segi * BSTG_CAP;
    const int* __restrict__ rp = g ? rp2 : rp1;
    const float* __restrict__ dinv = g ? dinv2 : dinv1;
    int2* __restrict__ pk = g ? pk2 : pk1;
    const int lo = b * BKT_W;
    int hi = lo + BKT_W;
    if (hi > NN) hi = NN;
    const int nw = hi - lo;
    for (int i = t; i < nw; i += 256) { fill[i] = 0; rps[i] = rp[lo + i]; }
    if (t == 0) rps[nw] = rp[hi];
    __syncthreads();
    const int segbase = rps[0];
    const int total = rps[nw] - segbase;
    for (int i = t; i < m; i += 256) {
        int2 e = seg[i];
        int dl = e.y - lo;
        int lp = rps[dl] - segbase + atomicAdd(&fill[dl], 1);
        if (lp < BSTG_CAP)
            sorted[lp] = make_int2(e.x, __float_as_int(dinv[e.x]));
    }
    __syncthreads();
    for (int i = t; i < total; i += 256)
        pk[segbase + i] = sorted[i];
}

// ---------------- W prep: emit W as bf16 hi/lo in EXACT MFMA fragment order ----------------
// Per layer, 32768 shorts = 64 KB laid out [hl(2)][colhalf(2)][grp=nt*4+ks(16)][lane(64)][e(8)].
// Fragment (hl,h,nt,ks,lane=(kg,lm),e) = bf16 of W^T[col=h*64+nt*16+lm][k=ks*32+kg*8+e].
// GEMM stages this linearly into LDS; every ds_read_b128 is lane-linear 1024B (conflict-free).
__global__ __launch_bounds__(256) void wprep_kernel(const float* __restrict__ W1, const float* __restrict__ W2,
                                                    const float* __restrict__ W3, const float* __restrict__ W4,
                                                    unsigned short* __restrict__ Wpk) {
    const int u = blockIdx.x * 256 + threadIdx.x;   // 0..131071
    const int layer = u >> 15;
    const int r = u & 32767;
    const int fidx = r >> 3, e = r & 7;
    const int lane = fidx & 63;
    const int q = fidx >> 6;             // 0..63
    const int grp = q & 15, hh = q >> 4; // hh = hl*2 + h
    const int hl = hh >> 1, h = hh & 1;
    const int nt = grp >> 2, ks = grp & 3;
    const int kg = lane >> 4, lm = lane & 15;
    const int ncol = h * 64 + nt * 16 + lm;
    const int kk = ks * 32 + kg * 8 + e;
    const float* __restrict__ W = layer == 0 ? W1 : layer == 1 ? W2 : layer == 2 ? W3 : W4;
    float v = W[kk * DF + ncol];
    unsigned short hi = f2bf(v);
    Wpk[u] = hl ? f2bf(v - BF2F(hi)) : hi;
}

// ---------------- H = X @ W via bf16x3-split MFMA, W fragments staged in LDS ----------------
// 8 waves: w = rg(4) x h(2). Wave computes rows rb..rb+15 x cols h*64..h*64+63 (4 nt tiles).
// A-frag: m=lm, k=kg*8+e (per 32-k block ks). D-frag: col=lm, row=kg*4+r (verified layout).
// acc = ah*bh; accl = al*bh + ah*bl  (split accumulators for shorter MFMA dep chains).
__global__ __launch_bounds__(512, 4) void gemm_mfma_kernel(const float* __restrict__ X,
                                                           const unsigned short* __restrict__ Wpk,
                                                           unsigned short* __restrict__ Hhi,
                                                           unsigned short* __restrict__ Hlo, int n) {
    __shared__ __align__(16) unsigned short smem[32768];   // 64 KB, mirrors Wpk layer layout
    const int t = threadIdx.x;
    const int lane = t & 63, w = t >> 6;
    const int h = w >> 2, rg = w & 3;
    const int lm = lane & 15, kg = lane >> 4;
    const int rb = blockIdx.x * GEMM_BLK_ROWS + rg * 16;
    const int row = rb + lm;

    // stage permuted W (hi+lo) into LDS: 4096 x 16B linear copy
    {
        const float4* __restrict__ g4 = (const float4*)Wpk;
        float4* s4 = (float4*)smem;
        #pragma unroll
        for (int i = 0; i < 8; i++) s4[t + 512 * i] = g4[t + 512 * i];
    }

    // load + split A fragments (read X once; hi/lo bf16 in registers) while stage lands
    bf16x8 ah[4], al[4];
    #pragma unroll
    for (int ks = 0; ks < 4; ks++) {
        float4 x0 = make_float4(0.f, 0.f, 0.f, 0.f), x1 = x0;
        if (row < n) {
            const float* xp = X + (size_t)row * DF + ks * 32 + kg * 8;
            x0 = *(const float4*)xp;
            x1 = *(const float4*)(xp + 4);
        }
        float xv[8] = {x0.x, x0.y, x0.z, x0.w, x1.x, x1.y, x1.z, x1.w};
        #pragma unroll
        for (int e = 0; e < 8; e++) {
            unsigned short hi = f2bf(xv[e]);
            float rem = xv[e] - BF2F(hi);
            ah[ks][e] = (short)hi;
            al[ks][e] = (short)f2bf(rem);
        }
    }
    __syncthreads();

    f32x4 acc[4], accl[4];
    #pragma unroll
    for (int nt = 0; nt < 4; nt++) { acc[nt] = (f32x4){0.f, 0.f, 0.f, 0.f}; accl[nt] = acc[nt]; }

    const unsigned short* __restrict__ bhb = smem + ((size_t)(h * 16) * 64 + lane) * 8;
    const unsigned short* __restrict__ blb = smem + ((size_t)((2 + h) * 16) * 64 + lane) * 8;
    #pragma unroll
    for (int nt = 0; nt < 4; nt++) {
        #pragma unroll
        for (int ks = 0; ks < 4; ks++) {
            const int grp = nt * 4 + ks;
            bf16x8 bh = *(const bf16x8*)(bhb + (size_t)grp * 512);
            bf16x8 bl = *(const bf16x8*)(blb + (size_t)grp * 512);
            acc[nt]  = __builtin_amdgcn_mfma_f32_16x16x32_bf16(ah[ks], bh, acc[nt], 0, 0, 0);
            accl[nt] = __builtin_amdgcn_mfma_f32_16x16x32_bf16(al[ks], bh, accl[nt], 0, 0, 0);
            accl[nt] = __builtin_amdgcn_mfma_f32_16x16x32_bf16(ah[ks], bl, accl[nt], 0, 0, 0);
        }
    }

    // epilogue: D layout col=lm, row=kg*4+r; write bf16 hi + bf16 lo (no fp32 H)
    const int rwb = rb + kg * 4;
    #pragma unroll
    for (int r = 0; r < 4; r++) {
        const int ro = rwb + r;
        if (ro < n) {
            #pragma unroll
            for (int nt = 0; nt < 4; nt++) {
                const int col = h * 64 + nt * 16 + lm;
                float v = acc[nt][r] + accl[nt][r];
                unsigned short hi = f2bf(v);
                Hhi[(size_t)ro * DF + col] = hi;
                Hlo[(size_t)ro * DF + col] = f2bf(v - BF2F(hi));
            }
        }
    }
}

// ---------------- aggregation: one wave per dst node, bf16 gathers ----------------
// out[i] = act( dinv[i]*sum coef[e]*Hhi[src[e]] + dinv[i]^2*(Hhi[i]+Hlo[i]) + b )
__global__ __launch_bounds__(256) void agg_kernel(const unsigned short* __restrict__ Hhi,
                                                  const unsigned short* __restrict__ Hlo,
                                                  const int* __restrict__ rp, const int2* __restrict__ pk,
                                                  const float* __restrict__ dinv, const float* __restrict__ bias,
                                                  float* __restrict__ out, int n, int act) {
    const int lane = threadIdx.x & 63;
    const int sub = lane & 31;
    const int half = lane >> 5;
    const int i = blockIdx.x * 4 + (threadIdx.x >> 6);
    if (i >= n) return;
    const int start = rp[i];
    const int end = rp[i + 1];
    float ax = 0.f, ay = 0.f, az = 0.f, aw = 0.f;
    const unsigned short* __restrict__ Hbc = Hhi + 4 * sub;
    for (int base = start; base < end; base += 64) {
        int cnt = end - base;
        if (cnt > 64) cnt = 64;
        int msrc = 0;
        float mdv = 0.f;
        if (lane < cnt) {  // coalesced 8B batch load of packed (src, coef)
            int2 pv = pk[base + lane];
            msrc = pv.x;
            mdv = __int_as_float(pv.y);
        }
        for (int j = 0; j < cnt; j += 16) {  // 16 edges per iter; 8 x 8B gathers in flight per half
            int e0 = j + half;               // halves take even/odd edges; pads have mdv==0
            int s[8]; float d[8];
            #pragma unroll
            for (int k = 0; k < 8; k++) {
                s[k] = __shfl(msrc, e0 + 2 * k);
                d[k] = __shfl(mdv, e0 + 2 * k);
            }
            ushort4 hb[8];
            #pragma unroll
            for (int k = 0; k < 8; k++) hb[k] = *(const ushort4*)(Hbc + (size_t)s[k] * DF);
            #pragma unroll
            for (int k = 0; k < 8; k++) {
                ax = fmaf(d[k], BF2F(hb[k].x), ax);
                ay = fmaf(d[k], BF2F(hb[k].y), ay);
                az = fmaf(d[k], BF2F(hb[k].z), az);
                aw = fmaf(d[k], BF2F(hb[k].w), aw);
            }
        }
    }
    // fold halves: lanes 0-31 += lanes 32-63
    ax += __shfl_down(ax, 32); ay += __shfl_down(ay, 32);
    az += __shfl_down(az, 32); aw += __shfl_down(aw, 32);
    if (half == 0) {
        float di = dinv[i];
        float dii = di * di;
        ushort4 hh4 = *(const ushort4*)(Hhi + (size_t)i * DF + 4 * sub);   // self term hi+lo ~ fp32
        ushort4 hl4 = *(const ushort4*)(Hlo + (size_t)i * DF + 4 * sub);
        float4 bv = *(const float4*)(bias + 4 * sub);
        float hx = BF2F(hh4.x) + BF2F(hl4.x);
        float hy = BF2F(hh4.y) + BF2F(hl4.y);
        float hz = BF2F(hh4.z) + BF2F(hl4.z);
        float hw = BF2F(hh4.w) + BF2F(hl4.w);
        float ox = fmaf(di, ax, fmaf(dii, hx, bv.x));
        float oy = fmaf(di, ay, fmaf(dii, hy, bv.y));
        float oz = fmaf(di, az, fmaf(dii, hz, bv.z));
        float ow = fmaf(di, aw, fmaf(dii, hw, bv.w));
        if (act == 0) {  // ELU
            ox = ox > 0.f ? ox : expm1f(ox);
            oy = oy > 0.f ? oy : expm1f(oy);
            oz = oz > 0.f ? oz : expm1f(oz);
            ow = ow > 0.f ? ow : expm1f(ow);
        } else {  // ReLU
            ox = fmaxf(ox, 0.f); oy = fmaxf(oy, 0.f);
            oz = fmaxf(oz, 0.f); ow = fmaxf(ow, 0.f);
        }
        float4 ov; ov.x = ox; ov.y = oy; ov.z = oz; ov.w = ow;
        *(float4*)(out + (size_t)i * DF + 4 * sub) = ov;
    }
}

extern "C" void kernel_launch(void* const* d_in, const int* in_sizes, int n_in,
                              void* d_out, int out_size, void* d_ws, size_t ws_size,
                              hipStream_t stream) {
    const float* x  = (const float*)d_in[0];
    const float* W1 = (const float*)d_in[1];
    const float* b1 = (const float*)d_in[2];
    const float* W2 = (const float*)d_in[3];
    const float* b2 = (const float*)d_in[4];
    const float* W3 = (const float*)d_in[5];
    const float* b3 = (const float*)d_in[6];
    const float* W4 = (const float*)d_in[7];
    const float* b4 = (const float*)d_in[8];
    const int* ei1 = (const int*)d_in[9];
    const int* ei2 = (const int*)d_in[10];
    const int *src1 = ei1, *dst1 = ei1 + NE;
    const int *src2 = ei2, *dst2 = ei2 + NE;

    // ---- workspace carve-out (512B aligned), ~83 MB ----
    char* ws = (char*)d_ws;
    size_t off = 0;
    auto carve = [&](size_t bytes) -> void* {
        void* p = (void*)(ws + off);
        off += (bytes + 511) & ~(size_t)511;
        return p;
    };
    int* stgcnt = (int*)carve((size_t)2 * NBKT * 4);
    size_t zero_bytes = off;                         // stgcnt zeroed
    int* cbase = (int*)carve((size_t)2 * NBKT * 4);
    float* dinv1 = (float*)carve((size_t)NN * 4);
    float* dinv2 = (float*)carve((size_t)NN * 4);
    int* rp1 = (int*)carve((size_t)(NN + 1) * 4);
    int* rp2 = (int*)carve((size_t)(NN + 1) * 4);
    int2* pk1 = (int2*)carve((size_t)NE * 8);
    int2* pk2 = (int2*)carve((size_t)NE * 8);
    int2* stg = (int2*)carve((size_t)2 * NBKT * BSTG_CAP * 8);           // 15.7 MB
    unsigned short* Hhi = (unsigned short*)carve((size_t)NN * DF * 2);   // 12.8 MB
    unsigned short* Hlo = (unsigned short*)carve((size_t)NN * DF * 2);   // 12.8 MB
    float* hbuf = (float*)carve((size_t)NN * DF * 4);                    // 25.6 MB
    unsigned short* Wpk = (unsigned short*)carve((size_t)4 * 32768 * 2); // 256 KB, fragment-ordered

    float* outz  = (float*)d_out;
    float* outxr = (float*)d_out + (size_t)NN * DF;

    const int gGemm = (NN + GEMM_BLK_ROWS - 1) / GEMM_BLK_ROWS;   // 782
    const int gAgg = (NN + 3) / 4;
    const int gBkt = 2 * NBKT;                            // 256 blocks
    const int WL = 32768;                                 // Wpk shorts per layer

    // ---- preprocessing: wprep -> bin128 -> bucketscan -> histrp -> place ----
    hipMemsetAsync(stgcnt, 0, zero_bytes, stream);
    wprep_kernel<<<512, 256, 0, stream>>>(W1, W2, W3, W4, Wpk);
    bin_kernel<<<BIN_BLOCKS, 256, 0, stream>>>(src1, dst1, src2, dst2, stg, stgcnt);
    chunkscan_kernel<<<1, 256, 0, stream>>>(stgcnt, cbase, rp1, rp2);
    histrp_kernel<<<gBkt, 256, 0, stream>>>(stg, stgcnt, cbase, rp1, dinv1, rp2, dinv2);
    place_kernel<<<gBkt, 256, 0, stream>>>(stg, stgcnt, rp1, rp2, dinv1, dinv2, pk1, pk2);

    // ---- layer 1: ELU(gcn(x, ei1, W1, b1)) -> hbuf ----
    gemm_mfma_kernel<<<gGemm, 512, 0, stream>>>(x, Wpk, Hhi, Hlo, NN);
    agg_kernel<<<gAgg, 256, 0, stream>>>(Hhi, Hlo, rp1, pk1, dinv1, b1, hbuf, NN, 0);
    // ---- layer 2: z = ELU(gcn(hbuf, ei2, W2, b2)) -> d_out ----
    gemm_mfma_kernel<<<gGemm, 512, 0, stream>>>(hbuf, Wpk + WL, Hhi, Hlo, NN);
    agg_kernel<<<gAgg, 256, 0, stream>>>(Hhi, Hlo, rp2, pk2, dinv2, b2, outz, NN, 0);
    // ---- layer 3: ELU(gcn(z, ei1, W3, b3)) -> hbuf ----
    gemm_mfma_kernel<<<gGemm, 512, 0, stream>>>(outz, Wpk + 2 * WL, Hhi, Hlo, NN);
    agg_kernel<<<gAgg, 256, 0, stream>>>(Hhi, Hlo, rp1, pk1, dinv1, b3, hbuf, NN, 0);
    // ---- layer 4: xr = ReLU(gcn(hbuf, ei2, W4, b4)) -> d_out[N*DF:] ----
    gemm_mfma_kernel<<<gGemm, 512, 0, stream>>>(hbuf, Wpk + 3 * WL, Hhi, Hlo, NN);
    agg_kernel<<<gAgg, 256, 0, stream>>>(Hhi, Hlo, rp2, pk2, dinv2, b4, outxr, NN, 1);
}